// Round 4
// baseline (195.521 us; speedup 1.0000x reference)
//
#include <hip/hip_runtime.h>

typedef float f32x4 __attribute__((ext_vector_type(4)));
typedef short s16x8 __attribute__((ext_vector_type(8)));
typedef unsigned int uint;
typedef uint u32x2 __attribute__((ext_vector_type(2)));
typedef uint u32x4 __attribute__((ext_vector_type(4)));

union Frag {
  u32x4 u;
  s16x8 s;
};

// pack two fp32 -> dword of two bf16 (round-half-up via +0x8000)
__device__ __forceinline__ uint packhi(float f0, float f1) {
  uint a = __float_as_uint(f0) + 0x8000u;
  uint b = __float_as_uint(f1) + 0x8000u;
  return __builtin_amdgcn_perm(b, a, 0x07060302u);  // [a.hi16 | b.hi16]
}

// split (f0,f1) into packed bf16 hi pair + packed bf16 residual pair
__device__ __forceinline__ void split2(float f0, float f1, uint& hi, uint& lw) {
  uint a0 = __float_as_uint(f0) + 0x8000u;
  uint a1 = __float_as_uint(f1) + 0x8000u;
  hi = __builtin_amdgcn_perm(a1, a0, 0x07060302u);
  float h0 = __uint_as_float(a0 & 0xFFFF0000u);
  float h1 = __uint_as_float(a1 & 0xFFFF0000u);
  lw = packhi(f0 - h0, f1 - h1);
}

// compiler-only fence: pins DS write->read program order (HW DS pipe is
// in-order within a wave, so no s_waitcnt needed between write and read).
#define CFENCE() __asm__ __volatile__("" ::: "memory")

// One wave per chain; 4 groups of 4 matrices. Phase A: 4 concurrent Horner
// expm's (ILP-4 on the LDS-roundtrip latency). Phase B: 4 serial chain steps.
__global__ __launch_bounds__(256, 4) void unitary_kernel(
    const float* __restrict__ x, float* __restrict__ out) {
  // stride-12 pair staging: pair t of col lo at [lo*12 + t]; hi and residual
  __shared__ uint TBH[4][4][192];
  __shared__ uint TBL[4][4][192];

  const int tid = threadIdx.x;
  const int w = tid >> 6;
  const int l = tid & 63;
  const int lo = l & 15;  // col (B/C/D) == row (A)
  const int g = l >> 4;
  const int gt = g & 1;
  const bool low = g < 2;

  const int ch = __builtin_amdgcn_readfirstlane(blockIdx.x * 4 + w);
  const float* xb =
      x + ((size_t)(127 - (ch >> 6)) * 1024 + (size_t)(ch & 63) * 16) * 256;

  f32x4 idm;
  idm[0] = (4 * g + 0 == lo) ? 1.f : 0.f;
  idm[1] = (4 * g + 1 == lo) ? 1.f : 0.f;
  idm[2] = (4 * g + 2 == lo) ? 1.f : 0.f;
  idm[3] = (4 * g + 3 == lo) ? 1.f : 0.f;

  const int wb = lo * 12 + 2 * g;   // C/D pack write: pairs 2g, 2g+1
  const int rbB = lo * 12 + 4 * gt; // B-frag read: pairs 4gt..4gt+3 (b128)

  f32x4 uc;

#pragma unroll 1
  for (int grp = 0; grp < 4; ++grp) {
    const float* xg = xb + (size_t)grp * 1024;
    // ---- phase A: load + init 4 matrices ----
    Frag xa[4];
    f32x4 t[4];
#pragma unroll
    for (int m = 0; m < 4; ++m) {
      const float* A = xg + m * 256;
      // A-frag(X^T): column loads (coalesced 64B per 16-lane group)
      float c0 = A[(8 * gt + 0) * 16 + lo], c1 = A[(8 * gt + 1) * 16 + lo];
      float c2 = A[(8 * gt + 2) * 16 + lo], c3 = A[(8 * gt + 3) * 16 + lo];
      float c4 = A[(8 * gt + 4) * 16 + lo], c5 = A[(8 * gt + 5) * 16 + lo];
      float c6 = A[(8 * gt + 6) * 16 + lo], c7 = A[(8 * gt + 7) * 16 + lo];
      // C/D(X^T) rows for the affine init
      f32x4 xr = *(const f32x4*)(A + lo * 16 + 4 * g);
      xa[m].u[0] = low ? packhi(c0, c1) : 0u;  // K upper half dead
      xa[m].u[1] = low ? packhi(c2, c3) : 0u;
      xa[m].u[2] = low ? packhi(c4, c5) : 0u;
      xa[m].u[3] = low ? packhi(c6, c7) : 0u;
#pragma unroll
      for (int i = 0; i < 4; ++i)  // T = c6*X + c5*I  (c_k = (-1)^k/k!)
        t[m][i] = fmaf(1.f / 720.f, xr[i], (-1.f / 120.f) * idm[i]);
    }
    // ---- phase A: 5 interleaved Horner steps ----
    const float SK[5] = {1.f / 24.f, -1.f / 6.f, 0.5f, -1.f, 1.f};
#pragma unroll
    for (int k = 0; k < 5; ++k) {
#pragma unroll
      for (int m = 0; m < 4; ++m) {
        u32x2 p = {packhi(t[m][0], t[m][1]), packhi(t[m][2], t[m][3])};
        *(u32x2*)&TBH[w][m][wb] = p;
      }
      CFENCE();
      Frag tb[4];
#pragma unroll
      for (int m = 0; m < 4; ++m) tb[m].u = *(const u32x4*)&TBH[w][m][rbB];
      CFENCE();
#pragma unroll
      for (int m = 0; m < 4; ++m) {
        f32x4 acc = idm * SK[k];
        t[m] = __builtin_amdgcn_mfma_f32_16x16x32_bf16(xa[m].s, tb[m].s, acc,
                                                       0, 0, 0);
      }
    }
    // ---- E -> A-frag registers ([Eh | El] along K) via hi/lo roundtrip ----
    Frag ea[4];
#pragma unroll
    for (int m = 0; m < 4; ++m) {
      uint h0, l0, h1, l1;
      split2(t[m][0], t[m][1], h0, l0);
      split2(t[m][2], t[m][3], h1, l1);
      *(u32x2*)&TBH[w][m][wb] = (u32x2){h0, h1};
      *(u32x2*)&TBL[w][m][wb] = (u32x2){l0, l1};
    }
    CFENCE();
#pragma unroll
    for (int m = 0; m < 4; ++m) {
      const uint* p = low ? &TBH[w][m][rbB] : &TBL[w][m][rbB];
      ea[m].u = *(const u32x4*)p;
    }
    CFENCE();
    // ---- phase B: 4 serial chain steps (U <- E@U, split-exact) ----
#pragma unroll
    for (int m = 0; m < 4; ++m) {
      if (grp == 0 && m == 0) {
        Frag ifr;  // B-frag of [I;I] (pairs with [Eh|El] -> exact E0)
        uint v = ((lo >> 3) == gt) ? (0x3F80u << (16 * (lo & 1))) : 0u;
        int slot = (lo >> 1) & 3;
        ifr.u[0] = (slot == 0) ? v : 0u;
        ifr.u[1] = (slot == 1) ? v : 0u;
        ifr.u[2] = (slot == 2) ? v : 0u;
        ifr.u[3] = (slot == 3) ? v : 0u;
        f32x4 z = {0.f, 0.f, 0.f, 0.f};
        uc = __builtin_amdgcn_mfma_f32_16x16x32_bf16(ea[0].s, ifr.s, z, 0, 0,
                                                     0);
      } else {
        uint h0, l0, h1, l1;
        split2(uc[0], uc[1], h0, l0);
        split2(uc[2], uc[3], h1, l1);
        *(u32x2*)&TBH[w][0][wb] = (u32x2){h0, h1};  // staging reuse (post-ea)
        *(u32x2*)&TBL[w][0][wb] = (u32x2){l0, l1};
        CFENCE();
        Frag b1, b2;  // [Uh;Uh], [Ul;Ul]
        b1.u = *(const u32x4*)&TBH[w][0][rbB];
        b2.u = *(const u32x4*)&TBL[w][0][rbB];
        CFENCE();
        f32x4 z = {0.f, 0.f, 0.f, 0.f};
        f32x4 t1 =
            __builtin_amdgcn_mfma_f32_16x16x32_bf16(ea[m].s, b1.s, z, 0, 0, 0);
        uc = __builtin_amdgcn_mfma_f32_16x16x32_bf16(ea[m].s, b2.s, t1, 0, 0,
                                                     0);
      }
    }
  }

  // store U (C/D -> row-major), 4x 256B coalesced segments
  float* op = out + (size_t)ch * 256;
  op[(4 * g + 0) * 16 + lo] = uc[0];
  op[(4 * g + 1) * 16 + lo] = uc[1];
  op[(4 * g + 2) * 16 + lo] = uc[2];
  op[(4 * g + 3) * 16 + lo] = uc[3];
}

extern "C" void kernel_launch(void* const* d_in, const int* in_sizes, int n_in,
                              void* d_out, int out_size, void* d_ws,
                              size_t ws_size, hipStream_t stream) {
  const float* x = (const float*)d_in[0];
  float* out = (float*)d_out;
  unitary_kernel<<<dim3(2048), dim3(256), 0, stream>>>(x, out);
}

// Round 5
// 192.616 us; speedup vs baseline: 1.0151x; 1.0151x over previous
//
#include <hip/hip_runtime.h>

typedef float f32x4 __attribute__((ext_vector_type(4)));
typedef _Float16 f16x2 __attribute__((ext_vector_type(2)));
typedef _Float16 f16x4 __attribute__((ext_vector_type(4)));

union H4 {
  f16x4 v;
  f16x2 p[2];
};

// compiler-only fence: pins DS write->read program order (same-wave DS pipe
// is in-order; compiler still inserts the lgkmcnt before first use).
#define CFENCE() __asm__ __volatile__("" ::: "memory")

// split fp32x4 into fp16 hi + fp16 residual (RTN scalar converts)
__device__ __forceinline__ void split4(f32x4 e, H4& hi, H4& lw) {
  _Float16 h0 = (_Float16)e[0], h1 = (_Float16)e[1];
  _Float16 h2 = (_Float16)e[2], h3 = (_Float16)e[3];
  hi.v = (f16x4){h0, h1, h2, h3};
  lw.v = (f16x4){(_Float16)(e[0] - (float)h0), (_Float16)(e[1] - (float)h1),
                 (_Float16)(e[2] - (float)h2), (_Float16)(e[3] - (float)h3)};
}

// U <- E @ U, split-fp16 exact-ish (drops El@Ul ~1e-6):
// all operands in-lane: B-frag(U) = packed C/D(U); A-frags eh/el prebuilt.
__device__ __forceinline__ void chain_step(f32x4& uc, const H4& eh,
                                           const H4& el) {
  H4 uh, ul;
  split4(uc, uh, ul);
  f32x4 z = {0.f, 0.f, 0.f, 0.f};
  f32x4 a = __builtin_amdgcn_mfma_f32_16x16x16f16(eh.v, ul.v, z, 0, 0, 0);
  a = __builtin_amdgcn_mfma_f32_16x16x16f16(el.v, uh.v, a, 0, 0, 0);
  uc = __builtin_amdgcn_mfma_f32_16x16x16f16(eh.v, uh.v, a, 0, 0, 0);
}

// One wave per chain. Horner Taylor order 6 per matrix, fully in-register
// (K=16 MFMA: C/D layout == pair-packed B-frag layout, zero cross-lane).
// Only A-frag(E) needs an LDS transpose, once per matrix.
__global__ __launch_bounds__(256, 8) void unitary_kernel(
    const float* __restrict__ x, float* __restrict__ out) {
  __shared__ float EF[4][2][16 * 20];  // per-wave E-transpose slots, stride 20

  const int tid = threadIdx.x;
  const int w = tid >> 6;
  const int l = tid & 63;
  const int lo = l & 15;  // col (B/C/D) == row (A)
  const int g = l >> 4;

  const int ch = blockIdx.x * 4 + w;  // chain 0..8191
  const float* xb =
      x + ((size_t)(127 - (ch >> 6)) * 1024 + (size_t)(ch & 63) * 16) * 256;

  f32x4 idm;
  idm[0] = (4 * g + 0 == lo) ? 1.f : 0.f;
  idm[1] = (4 * g + 1 == lo) ? 1.f : 0.f;
  idm[2] = (4 * g + 2 == lo) ? 1.f : 0.f;
  idm[3] = (4 * g + 3 == lo) ? 1.f : 0.f;

  float* ef0 = &EF[w][0][0];
  float* ef1 = &EF[w][1][0];

  // c_k = (-1)^k / k! for expm(-x); T0 = c6 I, then 6 Horner steps c5..c0
  const float SK[6] = {-1.f / 120.f, 1.f / 24.f, -1.f / 6.f, 0.5f, -1.f, 1.f};

  f32x4 uc;

#pragma unroll 1
  for (int grp = 0; grp < 8; ++grp) {
    const float* A0 = xb + (size_t)(2 * grp) * 256;
    const float* A1 = A0 + 256;
    // A-frag(X): row lo, cols 4g..4g+3 -> ONE contiguous dwordx4 per matrix
    f32x4 x0 = *(const f32x4*)(A0 + lo * 16 + 4 * g);
    f32x4 x1 = *(const f32x4*)(A1 + lo * 16 + 4 * g);
    H4 xa0, xa1;
    xa0.v = (f16x4){(_Float16)x0[0], (_Float16)x0[1], (_Float16)x0[2],
                    (_Float16)x0[3]};
    xa1.v = (f16x4){(_Float16)x1[0], (_Float16)x1[1], (_Float16)x1[2],
                    (_Float16)x1[3]};

    f32x4 t0 = idm * (1.f / 720.f);
    f32x4 t1 = t0;
#pragma unroll
    for (int k = 0; k < 6; ++k) {
      // B-frag(T) = packed C/D(T): in-lane, 4 converts per matrix
      H4 b0, b1;
      b0.v = (f16x4){(_Float16)t0[0], (_Float16)t0[1], (_Float16)t0[2],
                     (_Float16)t0[3]};
      b1.v = (f16x4){(_Float16)t1[0], (_Float16)t1[1], (_Float16)t1[2],
                     (_Float16)t1[3]};
      f32x4 a0 = idm * SK[k];
      f32x4 a1 = idm * SK[k];
      t0 = __builtin_amdgcn_mfma_f32_16x16x16f16(xa0.v, b0.v, a0, 0, 0, 0);
      t1 = __builtin_amdgcn_mfma_f32_16x16x16f16(xa1.v, b1.v, a1, 0, 0, 0);
    }
    // t0/t1 = C/D(E) fp32. Transpose through LDS once per matrix to get
    // A-frag(E): write rows (2-way bank aliasing = free), read row lo (b128).
#pragma unroll
    for (int i = 0; i < 4; ++i) {
      ef0[(4 * g + i) * 20 + lo] = t0[i];
      ef1[(4 * g + i) * 20 + lo] = t1[i];
    }
    CFENCE();
    f32x4 er0 = *(const f32x4*)&ef0[lo * 20 + 4 * g];
    f32x4 er1 = *(const f32x4*)&ef1[lo * 20 + 4 * g];
    CFENCE();
    H4 eh1, el1;
    split4(er1, eh1, el1);
    if (grp == 0) {
      uc = t0;  // U = E0 exact (C/D fp32); E0 never needs an A-frag
      chain_step(uc, eh1, el1);
    } else {
      H4 eh0, el0;
      split4(er0, eh0, el0);
      chain_step(uc, eh0, el0);
      chain_step(uc, eh1, el1);
    }
  }

  // store U (C/D -> row-major), 4 stores x 4 coalesced 64B segments
  float* op = out + (size_t)ch * 256;
  op[(4 * g + 0) * 16 + lo] = uc[0];
  op[(4 * g + 1) * 16 + lo] = uc[1];
  op[(4 * g + 2) * 16 + lo] = uc[2];
  op[(4 * g + 3) * 16 + lo] = uc[3];
}

extern "C" void kernel_launch(void* const* d_in, const int* in_sizes, int n_in,
                              void* d_out, int out_size, void* d_ws,
                              size_t ws_size, hipStream_t stream) {
  const float* x = (const float*)d_in[0];
  float* out = (float*)d_out;
  unitary_kernel<<<dim3(2048), dim3(256), 0, stream>>>(x, out);
}